// Round 18
// baseline (70.782 us; speedup 1.0000x reference)
//
#include <hip/hip_runtime.h>
#include <hip/hip_bf16.h>

#define N_NODES 4096
#define D_MODEL 256
#define NWORDS 128   // bitmap words per row (4096/32)
#define CAP 128      // max neighbors per row (avg ~33)

typedef __attribute__((ext_vector_type(8))) short short8;
typedef __attribute__((ext_vector_type(4))) short short4v;
typedef __attribute__((ext_vector_type(4))) float f32x4;

__device__ __forceinline__ unsigned short f2b(float f) {  // fp32 -> bf16 RTN
    unsigned u = __float_as_uint(f);
    return (unsigned short)((u + 0x7FFFu + ((u >> 16) & 1u)) >> 16);
}
__device__ __forceinline__ float b2f(unsigned short u) {
    return __uint_as_float((unsigned)u << 16);
}
__device__ __forceinline__ unsigned pk2(float lo, float hi) {  // 2xf32 -> packed bf16
    unsigned r;
    asm("v_cvt_pk_bf16_f32 %0, %1, %2" : "=v"(r) : "v"(lo), "v"(hi));
    return r;
}
__device__ __forceinline__ uint4 scale8(short8 v, float p) {   // bf16x8 * p -> bf16x8
    uint4 r;
    r.x = pk2(b2f((unsigned short)v[0]) * p, b2f((unsigned short)v[1]) * p);
    r.y = pk2(b2f((unsigned short)v[2]) * p, b2f((unsigned short)v[3]) * p);
    r.z = pk2(b2f((unsigned short)v[4]) * p, b2f((unsigned short)v[5]) * p);
    r.w = pk2(b2f((unsigned short)v[6]) * p, b2f((unsigned short)v[7]) * p);
    return r;
}

// ---- prep: convw tile-transpose (0..127) | zero bitmap (128..639)
// ----       | detect (640) | LN1 rows (641..4736) -------------------------
__global__ __launch_bounds__(256) void prep_kernel(const float* __restrict__ Wq,
        const float* __restrict__ Wk, const float* __restrict__ Wv,
        const float* __restrict__ Wo, const float* __restrict__ Wm1,
        const float* __restrict__ Wm2, unsigned short* __restrict__ wbf,
        uint4* __restrict__ bitmap, const int* __restrict__ ei,
        int* __restrict__ flag, const float* __restrict__ x,
        const float* __restrict__ g1, const float* __restrict__ b1,
        unsigned short* __restrict__ h) {
    int b = blockIdx.x, t = threadIdx.x;
    if (b < 128) {                        // coalesced W -> WT bf16 via LDS tiles
        const float* W; int base, K, M, kt, mt;
        if (b < 64)      { int r = b >> 4; W = (r == 0) ? Wq : (r == 1) ? Wk : (r == 2) ? Wv : Wo;
                           base = r << 16; K = 256; M = 256; kt = (b & 15) >> 2; mt = b & 3; }
        else if (b < 96) { W = Wm1; base = 262144; K = 256; M = 512; kt = (b - 64) >> 3; mt = (b - 64) & 7; }
        else             { W = Wm2; base = 393216; K = 512; M = 256; kt = (b - 96) >> 2; mt = (b - 96) & 3; }
        __shared__ unsigned short Lt[64][66];
        #pragma unroll
        for (int i = 0; i < 4; ++i) {     // read 64x64 f32 tile, coalesced float4
            int lin = i * 256 + t;
            int r = lin >> 4, c4 = (lin & 15) << 2;
            float4 v = *(const float4*)&W[(size_t)(kt * 64 + r) * M + mt * 64 + c4];
            Lt[r][c4 + 0] = f2b(v.x); Lt[r][c4 + 1] = f2b(v.y);
            Lt[r][c4 + 2] = f2b(v.z); Lt[r][c4 + 3] = f2b(v.w);
        }
        __syncthreads();
        #pragma unroll
        for (int i = 0; i < 2; ++i) {     // write transposed, coalesced short8
            int lin = i * 256 + t;
            int mr = lin >> 3, kc = (lin & 7) << 3;
            short8 o;
            #pragma unroll
            for (int e = 0; e < 8; ++e) o[e] = (short)Lt[kc + e][mr];
            *(short8*)&wbf[base + (size_t)(mt * 64 + mr) * K + kt * 64 + kc] = o;
        }
    } else if (b < 640) {                 // zero the 2MB bitmap
        bitmap[(size_t)(b - 128) * 256 + t] = uint4{0, 0, 0, 0};
    } else if (b == 640) {                // edge dtype detect
        if (t == 0) {
            int is64 = 1;
            for (int i = 1; i < 128; i += 2)
                if (ei[i] != 0) { is64 = 0; break; }
            *flag = is64;
        }
    } else {                              // LayerNorm1: one row per block
        int row = b - 641;
        float v = x[row * D_MODEL + t];
        __shared__ float red[4];
        float s = v;
        #pragma unroll
        for (int off = 32; off; off >>= 1) s += __shfl_down(s, off, 64);
        if ((t & 63) == 0) red[t >> 6] = s;
        __syncthreads();
        float mu = (red[0] + red[1] + red[2] + red[3]) * (1.0f / 256.0f);
        __syncthreads();
        float d = v - mu;
        float s2 = d * d;
        #pragma unroll
        for (int off = 32; off; off >>= 1) s2 += __shfl_down(s2, off, 64);
        if ((t & 63) == 0) red[t >> 6] = s2;
        __syncthreads();
        float var = (red[0] + red[1] + red[2] + red[3]) * (1.0f / 256.0f);
        h[row * D_MODEL + t] = f2b(d * rsqrtf(var + 1e-5f) * g1[t] + b1[t]);
    }
}

// ---- bf16 MFMA GEMM: BMx64 tile, 512 thr / 8 waves, BK=64 (BM=64 proven) -
// MODE 1: +bias,GELU -> bf16 | 2: +bias+R -> f32 | 3: qkv 3-part bias,
//   head-major stores q/k/v[h][N][32] (+ build_adj in blocks [0,nadj))
// LNA:   A is f32 + per-row partial stats -> layernorm during A-staging
// STATS: epilogue emits per-row partial sum/sumsq of C (BM=64 only)
template <int K, int BM, int MODE, bool LNA, bool STATS>
__global__ __launch_bounds__(512) void gemm_bf16(const unsigned short* __restrict__ A,
        const float* __restrict__ Af, const float* __restrict__ psum,
        const float* __restrict__ psum2, const float* __restrict__ lng,
        const float* __restrict__ lnb, const unsigned short* __restrict__ BT,
        const float* __restrict__ bias, const float* __restrict__ bias_k,
        const float* __restrict__ bias_v, const float* __restrict__ R,
        float* __restrict__ Cf, unsigned short* __restrict__ Cb,
        unsigned short* __restrict__ Ck, unsigned short* __restrict__ Cv,
        float* __restrict__ opsum, float* __restrict__ opsum2, int M,
        const int* __restrict__ ei, int E, const int* __restrict__ flag,
        unsigned* __restrict__ bitmap, int nadj) {
    constexpr int MR = BM / 64;
    constexpr int NRB = 4096 / BM;
    int tid = threadIdx.x;
    if (MODE == 3 && (int)blockIdx.x < nadj) {   // fused edge scatter
        int e = (int)blockIdx.x * 512 + tid;
        if (e < E) {
            int n, m;
            if (*flag) { n = ei[2 * e]; m = ei[2 * (E + e)]; }
            else       { n = ei[e];     m = ei[E + e]; }
            atomicOr(&bitmap[n * NWORDS + (m >> 5)], 1u << (m & 31));
        }
        return;
    }
    __shared__ unsigned short Asm[BM][72];
    __shared__ unsigned short Bsm[64][72];
    __shared__ float psA[64][2], psA2[64][2];
    __shared__ float muS[BM], invS[BM];

    int bx2  = (MODE == 3) ? ((int)blockIdx.x - nadj) : 0;
    int brow = (MODE == 3) ? ((bx2 % NRB) * BM) : ((int)blockIdx.x * BM);
    int by   = (MODE == 3) ? (bx2 / NRB) : (int)blockIdx.y;
    int bcol = by << 6;
    int wid = tid >> 6, lane = tid & 63;
    int wr = wid >> 1, wc = wid & 1;             // 4 row-waves x 2 col-waves
    int l15 = lane & 15, lhi = lane >> 4;
    int r0 = tid >> 3, c0 = (tid & 7) << 3;

    float mu_r[MR], inv_r[MR];
    if (LNA) {   // combine partial stats once per block
        if (tid < BM) {
            float4 s4 = ((const float4*)psum)[brow + tid];
            float4 q4 = ((const float4*)psum2)[brow + tid];
            float S  = s4.x + s4.y + s4.z + s4.w;
            float S2 = q4.x + q4.y + q4.z + q4.w;
            float mu = S * (1.0f / 256.0f);
            muS[tid] = mu;
            invS[tid] = rsqrtf(S2 * (1.0f / 256.0f) - mu * mu + 1e-5f);
        }
        __syncthreads();
        #pragma unroll
        for (int m = 0; m < MR; ++m) { mu_r[m] = muS[r0 + m * 64]; inv_r[m] = invS[r0 + m * 64]; }
    }

    const unsigned short* Bp = BT + (size_t)(bcol + r0) * K + c0;
    f32x4 acc[MR][2] = {};
    short8 areg[MR];
    float4 xa[MR], xb[MR], ga, gb, ba, bb;
    if (LNA) {
        #pragma unroll
        for (int m = 0; m < MR; ++m) {
            const float* Xp = Af + (size_t)(brow + r0 + m * 64) * 256 + c0;
            xa[m] = *(const float4*)(Xp);
            xb[m] = *(const float4*)(Xp + 4);
        }
        ga = *(const float4*)(lng + c0); gb = *(const float4*)(lng + c0 + 4);
        ba = *(const float4*)(lnb + c0); bb = *(const float4*)(lnb + c0 + 4);
    } else {
        #pragma unroll
        for (int m = 0; m < MR; ++m)
            areg[m] = *(const short8*)(A + (size_t)(brow + r0 + m * 64) * K + c0);
    }
    short8 breg = *(const short8*)(Bp);

    #pragma unroll
    for (int k0 = 0; k0 < K; k0 += 64) {
        if (LNA) {   // layernorm on the fly into LDS
            #pragma unroll
            for (int m = 0; m < MR; ++m) {
                float xv[8] = {xa[m].x, xa[m].y, xa[m].z, xa[m].w,
                               xb[m].x, xb[m].y, xb[m].z, xb[m].w};
                float gv[8] = {ga.x, ga.y, ga.z, ga.w, gb.x, gb.y, gb.z, gb.w};
                float bv[8] = {ba.x, ba.y, ba.z, ba.w, bb.x, bb.y, bb.z, bb.w};
                short8 o;
                #pragma unroll
                for (int j = 0; j < 8; ++j)
                    o[j] = (short)f2b((xv[j] - mu_r[m]) * inv_r[m] * gv[j] + bv[j]);
                *(short8*)&Asm[r0 + m * 64][c0] = o;
            }
        } else {
            #pragma unroll
            for (int m = 0; m < MR; ++m)
                *(short8*)&Asm[r0 + m * 64][c0] = areg[m];
        }
        *(short8*)&Bsm[r0][c0] = breg;
        __syncthreads();
        if (k0 + 64 < K) {                      // prefetch next K-step
            if (LNA) {
                #pragma unroll
                for (int m = 0; m < MR; ++m) {
                    const float* Xp = Af + (size_t)(brow + r0 + m * 64) * 256 + k0 + 64 + c0;
                    xa[m] = *(const float4*)(Xp);
                    xb[m] = *(const float4*)(Xp + 4);
                }
                ga = *(const float4*)(lng + k0 + 64 + c0);
                gb = *(const float4*)(lng + k0 + 64 + c0 + 4);
                ba = *(const float4*)(lnb + k0 + 64 + c0);
                bb = *(const float4*)(lnb + k0 + 64 + c0 + 4);
            } else {
                #pragma unroll
                for (int m = 0; m < MR; ++m)
                    areg[m] = *(const short8*)(A + (size_t)(brow + r0 + m * 64) * K + k0 + 64 + c0);
            }
            breg = *(const short8*)(Bp + k0 + 64);
        }
        #pragma unroll
        for (int ks = 0; ks < 2; ++ks) {
            int kc = ks * 32 + lhi * 8;
            short8 b_0 = *(const short8*)&Bsm[wc * 32 + l15][kc];
            short8 b_1 = *(const short8*)&Bsm[wc * 32 + 16 + l15][kc];
            #pragma unroll
            for (int sm = 0; sm < MR; ++sm) {
                short8 a_s = *(const short8*)&Asm[wr * 16 * MR + sm * 16 + l15][kc];
                acc[sm][0] = __builtin_amdgcn_mfma_f32_16x16x32_bf16(a_s, b_0, acc[sm][0], 0, 0, 0);
                acc[sm][1] = __builtin_amdgcn_mfma_f32_16x16x32_bf16(a_s, b_1, acc[sm][1], 0, 0, 0);
            }
        }
        __syncthreads();
    }

    float cs[2][4];
    #pragma unroll
    for (int sm = 0; sm < MR; ++sm)
        #pragma unroll
        for (int sn = 0; sn < 2; ++sn) {
            int col = bcol + wc * 32 + sn * 16 + l15;
            float bs;
            if (MODE == 3)
                bs = (col < 256) ? bias[col]
                   : (col < 512) ? bias_k[col - 256] : bias_v[col - 512];
            else
                bs = bias[col];
            #pragma unroll
            for (int r = 0; r < 4; ++r) {
                int row = brow + wr * 16 * MR + sm * 16 + lhi * 4 + r;
                float c = acc[sm][sn][r] + bs;
                if (MODE == 1) {
                    c = 0.5f * c * (1.0f + erff(c * 0.70710678118654752f));
                    Cb[(size_t)row * M + col] = f2b(c);
                } else if (MODE == 2) {
                    c += R[(size_t)row * M + col];
                    Cf[(size_t)row * M + col] = c;
                } else if (MODE == 3) {
                    // head-major: part (q/k/v), head = cc>>5, dim = cc&31
                    int part = col >> 8, cc = col & 255;
                    unsigned short* dst = (part == 0) ? Cb : (part == 1) ? Ck : Cv;
                    dst[(((size_t)(cc >> 5) * N_NODES + row) << 5) + (cc & 31)] = f2b(c);
                } else {
                    Cb[(size_t)row * M + col] = f2b(c);
                }
                if (STATS) cs[sn][r] = c;
            }
        }
    if (STATS) {   // per-row partial stats over this 64-col strip (BM=64)
        #pragma unroll
        for (int r = 0; r < 4; ++r) {
            float s  = cs[0][r] + cs[1][r];
            float s2 = cs[0][r] * cs[0][r] + cs[1][r] * cs[1][r];
            #pragma unroll
            for (int off = 1; off < 16; off <<= 1) {
                s  += __shfl_xor(s, off, 64);
                s2 += __shfl_xor(s2, off, 64);
            }
            if (l15 == 0) {
                int rl = wr * 16 + lhi * 4 + r;
                psA[rl][wc] = s; psA2[rl][wc] = s2;
            }
        }
        __syncthreads();
        if (tid < 64) {
            opsum [(size_t)(brow + tid) * 4 + by] = psA[tid][0] + psA[tid][1];
            opsum2[(size_t)(brow + tid) * 4 + by] = psA2[tid][0] + psA2[tid][1];
        }
    }
}

// ---------------- sparse attention: one (row,head) task per 64-lane wave --
// head = blockIdx.x & 7 (XCD L2 pinning). Unified online-softmax loop over
// 64-neighbor batches (register-reusing; c<=64 degenerates to single pass).
// q kept as bf16 regs (-16 VGPR); p-scaled V staged to per-wave LDS; PV =
// 8 ds_read_b64_tr_b16 + shfl_xor(32) combine. launch_bounds(256,4) caps
// VGPR at 128 -> 4 waves/EU for latency hiding.
#define TRLOAD(dst_, OFF_) \
    asm volatile("ds_read_b64_tr_b16 %0, %1 offset:" #OFF_ \
                 : "=v"(dst_) : "v"(trbase))
#define PVSUM(tv_) { \
    acc0 += b2f((unsigned short)tv_[0]); acc1 += b2f((unsigned short)tv_[1]); \
    acc0 += b2f((unsigned short)tv_[2]); acc1 += b2f((unsigned short)tv_[3]); }

__global__ __launch_bounds__(256, 4) void attn_kernel(const unsigned short* __restrict__ qh,
        const unsigned short* __restrict__ kh, const unsigned short* __restrict__ vh,
        const unsigned* __restrict__ bitmap, unsigned short* __restrict__ y) {
    int bid = blockIdx.x, tid = threadIdx.x;
    int h = bid & 7;                       // all waves of this block: one head
    int wid = tid >> 6, lane = tid & 63;
    int n = ((bid >> 3) << 2) + wid;       // 8192 blocks x 4 waves = 4096 rows
    __shared__ int sIdx[4][CAP];
    __shared__ unsigned short Vst[4][2176];   // 16 jblocks x 136 (4x16 subtiles + pad)

    // q as bf16 regs (no reuse within task -> convert inline in the dot)
    const unsigned short* qp = qh + (((size_t)h * N_NODES + n) << 5);
    short8 q0 = *(const short8*)(qp);      short8 q1 = *(const short8*)(qp + 8);
    short8 q2 = *(const short8*)(qp + 16); short8 q3 = *(const short8*)(qp + 24);

    // bitmap scan: lane owns 2 words (uint2), prefix over 64 lanes
    uint2 w2 = ((const uint2*)(bitmap + (size_t)n * NWORDS))[lane];
    unsigned words[2] = {w2.x, w2.y};
    int pc = __popc(w2.x) + __popc(w2.y);
    int pre = pc;
    #pragma unroll
    for (int off = 1; off < 64; off <<= 1) {
        int u = __shfl_up(pre, off, 64);
        if (lane >= off) pre += u;
    }
    int c = __shfl(pre, 63, 64);
    int off = pre - pc;
    #pragma unroll
    for (int i = 0; i < 2; ++i) {
        unsigned word = words[i];
        int wbase = ((lane << 1) + i) << 5;
        while (word) {
            int bit = __ffs(word) - 1;
            word &= word - 1;
            if (off < CAP) sIdx[wid][off] = wbase + bit;
            ++off;
        }
    }
    c = min(c, CAP);
    for (int i = c + lane; i < CAP; i += 64) sIdx[wid][i] = 0;   // pad: safe index
    // (per-wave LDS: no block barrier needed)

    const size_t hb = (size_t)h * N_NODES << 5;
    const float sc = 0.17677669529663687f;   // 1/sqrt(32)
    float m_run = -INFINITY, S = 0.0f, acc = 0.0f;

    for (int b0 = 0; b0 < c; b0 += 64) {
        int j = b0 + lane;
        int idx = sIdx[wid][j < CAP ? j : CAP - 1];

        // V load first (consumed after softmax — long latency window)
        const unsigned short* va = vh + hb + ((size_t)idx << 5);
        short8 v0 = *(const short8*)(va);      short8 v1 = *(const short8*)(va + 8);
        short8 v2 = *(const short8*)(va + 16); short8 v3 = *(const short8*)(va + 24);
        // K gather
        const unsigned short* ka = kh + hb + ((size_t)idx << 5);
        short8 k0 = *(const short8*)(ka);      short8 k1 = *(const short8*)(ka + 8);
        short8 k2 = *(const short8*)(ka + 16); short8 k3 = *(const short8*)(ka + 24);

        float d0 = 0.f, d1 = 0.f, d2 = 0.f, d3 = 0.f;
        #pragma unroll
        for (int e = 0; e < 8; ++e) {
            d0 = fmaf(b2f((unsigned short)q0[e]), b2f((unsigned short)k0[e]), d0);
            d1 = fmaf(b2f((unsigned short)q1[e]), b2f((unsigned short)k1[e]), d1);
            d2 = fmaf(b2f((unsigned short)q2[e]), b2f((unsigned short)k2[e]), d2);
            d3 = fmaf(b2f((unsigned short)q3[e]), b2f((unsigned short)k3[e]), d3);
        }
        float s = (j < c) ? ((d0 + d1) + (d2 + d3)) * sc : -INFINITY;

        // online softmax over this 64-batch
        float bm = s;
        #pragma unroll
        for (int o2 = 32; o2; o2 >>= 1) bm = fmaxf(bm, __shfl_xor(bm, o2, 64));
        float newM = fmaxf(m_run, bm);
        float p = (j < c) ? __expf(s - newM) : 0.0f;
        float bs = p;
        #pragma unroll
        for (int o2 = 32; o2; o2 >>= 1) bs += __shfl_xor(bs, o2, 64);
        float rsc = __expf(m_run - newM);    // exp(-inf)=0 on first batch
        S = S * rsc + bs;
        acc *= rsc;
        m_run = newM;

        // stage p-scaled V: elem(j,d) = (j>>2)*136 + (d>>4)*64 + (j&3)*16 + (d&15)
        {
            unsigned short* vr = &Vst[wid][(lane >> 2) * 136 + (lane & 3) * 16];
            *(uint4*)(vr + 0)  = scale8(v0, p);
            *(uint4*)(vr + 8)  = scale8(v1, p);
            *(uint4*)(vr + 64) = scale8(v2, p);
            *(uint4*)(vr + 72) = scale8(v3, p);
        }

        // PV: 8 tr-reads; lane&31 = output dim, lane>>5 = j-block parity (+272B)
        unsigned trbase = (unsigned)(uintptr_t)(&Vst[wid][0])
                        + ((unsigned)(lane >> 5) * 272u)
                        + (((unsigned)(lane >> 4) & 1u) << 7) + ((unsigned)(lane & 15) << 3);
        asm volatile("s_waitcnt lgkmcnt(0)" ::: "memory");   // Vst written
        short4v t0, t1, t2, t3, t4, t5, t6, t7;
        TRLOAD(t0, 0);    TRLOAD(t1, 544);  TRLOAD(t2, 1088); TRLOAD(t3, 1632);
        TRLOAD(t4, 2176); TRLOAD(t5, 2720); TRLOAD(t6, 3264); TRLOAD(t7, 3808);
        asm volatile("s_waitcnt lgkmcnt(0)" ::: "memory");
        __builtin_amdgcn_sched_barrier(0);

        float acc0 = 0.0f, acc1 = 0.0f;
        PVSUM(t0) PVSUM(t1) PVSUM(t2) PVSUM(t3)
        PVSUM(t4) PVSUM(t5) PVSUM(t6) PVSUM(t7)
        acc += acc0 + acc1;
    }

    float tot = acc + __shfl_xor(acc, 32, 64);   // combine even/odd j-block halves
    if (lane < 32)
        y[(size_t)n * 256 + h * 32 + lane] = f2b(tot / S);
}

extern "C" void kernel_launch(void* const* d_in, const int* in_sizes, int n_in,
                              void* d_out, int out_size, void* d_ws, size_t ws_size,
                              hipStream_t stream) {
    const float* x   = (const float*)d_in[0];
    const int*   ei  = (const int*)d_in[1];
    const float* Wq  = (const float*)d_in[2];  const float* bq  = (const float*)d_in[3];
    const float* Wk  = (const float*)d_in[4];  const float* bk  = (const float*)d_in[5];
    const float* Wv  = (const float*)d_in[6];  const float* bv  = (const float*)d_in[7];
    const float* Wo  = (const float*)d_in[8];  const float* bo  = (const float*)d_in[9];
    const float* g1  = (const float*)d_in[10]; const float* b1  = (const float*)d_in[11];
    const float* g2  = (const float*)d_in[12]; const float* b2  = (const float*)d_in[13];
    const float* Wm1 = (const float*)d_in[14]; const float* bm1 = (const float*)d_in[15];
    const float* Wm2 = (const float*)d_in[16]; const float* bm2 = (const float*)d_in[17];
    float* out = (float*)d_out;
    int E = in_sizes[1] / 2;   // 135168
    int nadj = (E + 511) / 512;

    char* WS = (char*)d_ws;
    const size_t MB = 1u << 20;
    unsigned*       bitmap = (unsigned*)WS;                        // [0,2MB)
    int*            flag   = (int*)(WS + 2 * MB);                  // 4B
    float*          psum   = (float*)(WS + 2 * MB + 4096);         // 64KB [N][4]
    float*          psum2  = (float*)(WS + 2 * MB + 4096 + 65536); // 64KB
    unsigned short* wbf    = (unsigned short*)(WS + 3 * MB);       // 1MB
    unsigned short* y      = (unsigned short*)(WS + 4 * MB);       // 2MB
    float*          x1     = (float*)(WS + 6 * MB);                // 4MB
    unsigned short* m1     = (unsigned short*)(WS + 10 * MB);      // 4MB
    unsigned short* h      = (unsigned short*)(WS + 14 * MB);      // 2MB
    unsigned short* qh     = (unsigned short*)(WS + 16 * MB);      // 2MB [8][N][32]
    unsigned short* kh     = (unsigned short*)(WS + 18 * MB);      // 2MB
    unsigned short* vh     = (unsigned short*)(WS + 20 * MB);      // 2MB

    const unsigned short* WTqkv = wbf;            // q|k|v stacked along M
    const unsigned short* WTo   = wbf + 196608;
    const unsigned short* WTm1  = wbf + 262144;
    const unsigned short* WTm2  = wbf + 393216;

    // 1) convw (tiled transpose) + zero bitmap + detect + LN1
    prep_kernel<<<4737, 256, 0, stream>>>(Wq, Wk, Wv, Wo, Wm1, Wm2, wbf,
                                          (uint4*)bitmap, ei, flag, x, g1, b1, h);
    // 2) build_adj (blocks [0,nadj)) + qkv GEMM (BM=64), head-major stores
    gemm_bf16<256, 64, 3, false, false><<<nadj + 768, 512, 0, stream>>>(h, nullptr,
            nullptr, nullptr, nullptr, nullptr, WTqkv, bq, bk, bv, nullptr,
            nullptr, qh, kh, vh, nullptr, nullptr, 768, ei, E, flag, bitmap, nadj);
    // 3) attention (wave64 per task, XCD-pinned heads, unified online loop)
    attn_kernel<<<8192, 256, 0, stream>>>(qh, kh, vh, bitmap, y);
    // 4) x1 = x + y @ Wo + bo   (+ per-row partial LN2 stats)
    gemm_bf16<256, 64, 2, false, true><<<dim3(64, 4), 512, 0, stream>>>(y, nullptr,
            nullptr, nullptr, nullptr, nullptr, WTo, bo, nullptr, nullptr, x,
            x1, nullptr, nullptr, nullptr, psum, psum2, 256, nullptr, 0, nullptr, nullptr, 0);
    // 5) m1 = gelu(LN2(x1) @ Wm1 + bm1)   (LN2 during A-staging, BM=64)
    gemm_bf16<256, 64, 1, true, false><<<dim3(64, 8), 512, 0, stream>>>(nullptr, x1,
            psum, psum2, g2, b2, WTm1, bm1, nullptr, nullptr, nullptr,
            nullptr, m1, nullptr, nullptr, nullptr, nullptr, 512, nullptr, 0, nullptr, nullptr, 0);
    // 6) out = x1 + m1 @ Wm2 + bm2
    gemm_bf16<512, 64, 2, false, false><<<dim3(64, 4), 512, 0, stream>>>(m1, nullptr,
            nullptr, nullptr, nullptr, nullptr, WTm2, bm2, nullptr, nullptr, x1,
            out, nullptr, nullptr, nullptr, nullptr, nullptr, 256, nullptr, 0, nullptr, nullptr, 0);
}

// Round 19
// 65.910 us; speedup vs baseline: 1.0739x; 1.0739x over previous
//
#include <hip/hip_runtime.h>
#include <hip/hip_bf16.h>

#define N_NODES 4096
#define D_MODEL 256
#define NWORDS 128   // bitmap words per row (4096/32)
#define CAP 128      // max neighbors per row (avg ~33)

typedef __attribute__((ext_vector_type(8))) short short8;
typedef __attribute__((ext_vector_type(4))) short short4v;
typedef __attribute__((ext_vector_type(4))) float f32x4;

__device__ __forceinline__ unsigned short f2b(float f) {  // fp32 -> bf16 RTN
    unsigned u = __float_as_uint(f);
    return (unsigned short)((u + 0x7FFFu + ((u >> 16) & 1u)) >> 16);
}
__device__ __forceinline__ float b2f(unsigned short u) {
    return __uint_as_float((unsigned)u << 16);
}
__device__ __forceinline__ unsigned pk2(float lo, float hi) {  // 2xf32 -> packed bf16
    unsigned r;
    asm("v_cvt_pk_bf16_f32 %0, %1, %2" : "=v"(r) : "v"(lo), "v"(hi));
    return r;
}
__device__ __forceinline__ uint4 scale8(short8 v, float p) {   // bf16x8 * p -> bf16x8
    uint4 r;
    r.x = pk2(b2f((unsigned short)v[0]) * p, b2f((unsigned short)v[1]) * p);
    r.y = pk2(b2f((unsigned short)v[2]) * p, b2f((unsigned short)v[3]) * p);
    r.z = pk2(b2f((unsigned short)v[4]) * p, b2f((unsigned short)v[5]) * p);
    r.w = pk2(b2f((unsigned short)v[6]) * p, b2f((unsigned short)v[7]) * p);
    return r;
}

// ---- prep: convw tile-transpose (0..127) | zero bitmap (128..639)
// ----       | detect (640) | LN1 wave-per-row (641..1664) -----------------
__global__ __launch_bounds__(256) void prep_kernel(const float* __restrict__ Wq,
        const float* __restrict__ Wk, const float* __restrict__ Wv,
        const float* __restrict__ Wo, const float* __restrict__ Wm1,
        const float* __restrict__ Wm2, unsigned short* __restrict__ wbf,
        uint4* __restrict__ bitmap, const int* __restrict__ ei,
        int* __restrict__ flag, const float* __restrict__ x,
        const float* __restrict__ g1, const float* __restrict__ b1,
        unsigned short* __restrict__ h) {
    int b = blockIdx.x, t = threadIdx.x;
    if (b < 128) {                        // coalesced W -> WT bf16 via LDS tiles
        const float* W; int base, K, M, kt, mt;
        if (b < 64)      { int r = b >> 4; W = (r == 0) ? Wq : (r == 1) ? Wk : (r == 2) ? Wv : Wo;
                           base = r << 16; K = 256; M = 256; kt = (b & 15) >> 2; mt = b & 3; }
        else if (b < 96) { W = Wm1; base = 262144; K = 256; M = 512; kt = (b - 64) >> 3; mt = (b - 64) & 7; }
        else             { W = Wm2; base = 393216; K = 512; M = 256; kt = (b - 96) >> 2; mt = (b - 96) & 3; }
        __shared__ unsigned short Lt[64][66];
        #pragma unroll
        for (int i = 0; i < 4; ++i) {     // read 64x64 f32 tile, coalesced float4
            int lin = i * 256 + t;
            int r = lin >> 4, c4 = (lin & 15) << 2;
            float4 v = *(const float4*)&W[(size_t)(kt * 64 + r) * M + mt * 64 + c4];
            Lt[r][c4 + 0] = f2b(v.x); Lt[r][c4 + 1] = f2b(v.y);
            Lt[r][c4 + 2] = f2b(v.z); Lt[r][c4 + 3] = f2b(v.w);
        }
        __syncthreads();
        #pragma unroll
        for (int i = 0; i < 2; ++i) {     // write transposed, coalesced short8
            int lin = i * 256 + t;
            int mr = lin >> 3, kc = (lin & 7) << 3;
            short8 o;
            #pragma unroll
            for (int e = 0; e < 8; ++e) o[e] = (short)Lt[kc + e][mr];
            *(short8*)&wbf[base + (size_t)(mt * 64 + mr) * K + kt * 64 + kc] = o;
        }
    } else if (b < 640) {                 // zero the 2MB bitmap
        bitmap[(size_t)(b - 128) * 256 + t] = uint4{0, 0, 0, 0};
    } else if (b == 640) {                // edge dtype detect
        if (t == 0) {
            int is64 = 1;
            for (int i = 1; i < 128; i += 2)
                if (ei[i] != 0) { is64 = 0; break; }
            *flag = is64;
        }
    } else {                              // LN1: wave per row (no LDS/barriers)
        int wid = t >> 6, lane = t & 63;
        int row = ((b - 641) << 2) + wid;
        float4 xv = *(const float4*)&x[(size_t)row * 256 + lane * 4];
        float s  = xv.x + xv.y + xv.z + xv.w;
        float s2 = xv.x * xv.x + xv.y * xv.y + xv.z * xv.z + xv.w * xv.w;
        #pragma unroll
        for (int off = 32; off; off >>= 1) {
            s  += __shfl_xor(s, off, 64);
            s2 += __shfl_xor(s2, off, 64);
        }
        float mu  = s * (1.0f / 256.0f);
        float inv = rsqrtf(s2 * (1.0f / 256.0f) - mu * mu + 1e-5f);
        float4 gv = *(const float4*)&g1[lane * 4];
        float4 bv = *(const float4*)&b1[lane * 4];
        short4v o;
        o.x = (short)f2b((xv.x - mu) * inv * gv.x + bv.x);
        o.y = (short)f2b((xv.y - mu) * inv * gv.y + bv.y);
        o.z = (short)f2b((xv.z - mu) * inv * gv.z + bv.z);
        o.w = (short)f2b((xv.w - mu) * inv * gv.w + bv.w);
        *(short4v*)&h[(size_t)row * 256 + lane * 4] = o;
    }
}

// ---- bf16 MFMA GEMM: BMx64 tile, 512 thr / 8 waves, BK=64 (BM=64 proven) -
// MODE 1: +bias,GELU -> bf16 | 2: +bias+R -> f32 | 3: qkv 3-part bias,
//   head-major stores q/k/v[h][N][32] (+ build_adj in blocks [0,nadj))
// LNA:   A is f32 + per-row partial stats -> layernorm during A-staging
// STATS: epilogue emits per-row partial sum/sumsq of C (BM=64 only)
template <int K, int BM, int MODE, bool LNA, bool STATS>
__global__ __launch_bounds__(512) void gemm_bf16(const unsigned short* __restrict__ A,
        const float* __restrict__ Af, const float* __restrict__ psum,
        const float* __restrict__ psum2, const float* __restrict__ lng,
        const float* __restrict__ lnb, const unsigned short* __restrict__ BT,
        const float* __restrict__ bias, const float* __restrict__ bias_k,
        const float* __restrict__ bias_v, const float* __restrict__ R,
        float* __restrict__ Cf, unsigned short* __restrict__ Cb,
        unsigned short* __restrict__ Ck, unsigned short* __restrict__ Cv,
        float* __restrict__ opsum, float* __restrict__ opsum2, int M,
        const int* __restrict__ ei, int E, const int* __restrict__ flag,
        unsigned* __restrict__ bitmap, int nadj) {
    constexpr int MR = BM / 64;
    constexpr int NRB = 4096 / BM;
    int tid = threadIdx.x;
    if (MODE == 3 && (int)blockIdx.x < nadj) {   // fused edge scatter
        int e = (int)blockIdx.x * 512 + tid;
        if (e < E) {
            int n, m;
            if (*flag) { n = ei[2 * e]; m = ei[2 * (E + e)]; }
            else       { n = ei[e];     m = ei[E + e]; }
            atomicOr(&bitmap[n * NWORDS + (m >> 5)], 1u << (m & 31));
        }
        return;
    }
    __shared__ unsigned short Asm[BM][72];
    __shared__ unsigned short Bsm[64][72];
    __shared__ float psA[64][2], psA2[64][2];
    __shared__ float muS[BM], invS[BM];

    int bx2  = (MODE == 3) ? ((int)blockIdx.x - nadj) : 0;
    int brow = (MODE == 3) ? ((bx2 % NRB) * BM) : ((int)blockIdx.x * BM);
    int by   = (MODE == 3) ? (bx2 / NRB) : (int)blockIdx.y;
    int bcol = by << 6;
    int wid = tid >> 6, lane = tid & 63;
    int wr = wid >> 1, wc = wid & 1;             // 4 row-waves x 2 col-waves
    int l15 = lane & 15, lhi = lane >> 4;
    int r0 = tid >> 3, c0 = (tid & 7) << 3;

    float mu_r[MR], inv_r[MR];
    if (LNA) {   // combine partial stats once per block
        if (tid < BM) {
            float4 s4 = ((const float4*)psum)[brow + tid];
            float4 q4 = ((const float4*)psum2)[brow + tid];
            float S  = s4.x + s4.y + s4.z + s4.w;
            float S2 = q4.x + q4.y + q4.z + q4.w;
            float mu = S * (1.0f / 256.0f);
            muS[tid] = mu;
            invS[tid] = rsqrtf(S2 * (1.0f / 256.0f) - mu * mu + 1e-5f);
        }
        __syncthreads();
        #pragma unroll
        for (int m = 0; m < MR; ++m) { mu_r[m] = muS[r0 + m * 64]; inv_r[m] = invS[r0 + m * 64]; }
    }

    const unsigned short* Bp = BT + (size_t)(bcol + r0) * K + c0;
    f32x4 acc[MR][2] = {};
    short8 areg[MR];
    float4 xa[MR], xb[MR], ga, gb, ba, bb;
    if (LNA) {
        #pragma unroll
        for (int m = 0; m < MR; ++m) {
            const float* Xp = Af + (size_t)(brow + r0 + m * 64) * 256 + c0;
            xa[m] = *(const float4*)(Xp);
            xb[m] = *(const float4*)(Xp + 4);
        }
        ga = *(const float4*)(lng + c0); gb = *(const float4*)(lng + c0 + 4);
        ba = *(const float4*)(lnb + c0); bb = *(const float4*)(lnb + c0 + 4);
    } else {
        #pragma unroll
        for (int m = 0; m < MR; ++m)
            areg[m] = *(const short8*)(A + (size_t)(brow + r0 + m * 64) * K + c0);
    }
    short8 breg = *(const short8*)(Bp);

    #pragma unroll
    for (int k0 = 0; k0 < K; k0 += 64) {
        if (LNA) {   // layernorm on the fly into LDS
            #pragma unroll
            for (int m = 0; m < MR; ++m) {
                float xv[8] = {xa[m].x, xa[m].y, xa[m].z, xa[m].w,
                               xb[m].x, xb[m].y, xb[m].z, xb[m].w};
                float gv[8] = {ga.x, ga.y, ga.z, ga.w, gb.x, gb.y, gb.z, gb.w};
                float bv[8] = {ba.x, ba.y, ba.z, ba.w, bb.x, bb.y, bb.z, bb.w};
                short8 o;
                #pragma unroll
                for (int j = 0; j < 8; ++j)
                    o[j] = (short)f2b((xv[j] - mu_r[m]) * inv_r[m] * gv[j] + bv[j]);
                *(short8*)&Asm[r0 + m * 64][c0] = o;
            }
        } else {
            #pragma unroll
            for (int m = 0; m < MR; ++m)
                *(short8*)&Asm[r0 + m * 64][c0] = areg[m];
        }
        *(short8*)&Bsm[r0][c0] = breg;
        __syncthreads();
        if (k0 + 64 < K) {                      // prefetch next K-step
            if (LNA) {
                #pragma unroll
                for (int m = 0; m < MR; ++m) {
                    const float* Xp = Af + (size_t)(brow + r0 + m * 64) * 256 + k0 + 64 + c0;
                    xa[m] = *(const float4*)(Xp);
                    xb[m] = *(const float4*)(Xp + 4);
                }
                ga = *(const float4*)(lng + k0 + 64 + c0);
                gb = *(const float4*)(lng + k0 + 64 + c0 + 4);
                ba = *(const float4*)(lnb + k0 + 64 + c0);
                bb = *(const float4*)(lnb + k0 + 64 + c0 + 4);
            } else {
                #pragma unroll
                for (int m = 0; m < MR; ++m)
                    areg[m] = *(const short8*)(A + (size_t)(brow + r0 + m * 64) * K + k0 + 64 + c0);
            }
            breg = *(const short8*)(Bp + k0 + 64);
        }
        #pragma unroll
        for (int ks = 0; ks < 2; ++ks) {
            int kc = ks * 32 + lhi * 8;
            short8 b_0 = *(const short8*)&Bsm[wc * 32 + l15][kc];
            short8 b_1 = *(const short8*)&Bsm[wc * 32 + 16 + l15][kc];
            #pragma unroll
            for (int sm = 0; sm < MR; ++sm) {
                short8 a_s = *(const short8*)&Asm[wr * 16 * MR + sm * 16 + l15][kc];
                acc[sm][0] = __builtin_amdgcn_mfma_f32_16x16x32_bf16(a_s, b_0, acc[sm][0], 0, 0, 0);
                acc[sm][1] = __builtin_amdgcn_mfma_f32_16x16x32_bf16(a_s, b_1, acc[sm][1], 0, 0, 0);
            }
        }
        __syncthreads();
    }

    float cs[2][4];
    #pragma unroll
    for (int sm = 0; sm < MR; ++sm)
        #pragma unroll
        for (int sn = 0; sn < 2; ++sn) {
            int col = bcol + wc * 32 + sn * 16 + l15;
            float bs;
            if (MODE == 3)
                bs = (col < 256) ? bias[col]
                   : (col < 512) ? bias_k[col - 256] : bias_v[col - 512];
            else
                bs = bias[col];
            #pragma unroll
            for (int r = 0; r < 4; ++r) {
                int row = brow + wr * 16 * MR + sm * 16 + lhi * 4 + r;
                float c = acc[sm][sn][r] + bs;
                if (MODE == 1) {
                    c = 0.5f * c * (1.0f + erff(c * 0.70710678118654752f));
                    Cb[(size_t)row * M + col] = f2b(c);
                } else if (MODE == 2) {
                    c += R[(size_t)row * M + col];
                    Cf[(size_t)row * M + col] = c;
                } else if (MODE == 3) {
                    // head-major: part (q/k/v), head = cc>>5, dim = cc&31
                    int part = col >> 8, cc = col & 255;
                    unsigned short* dst = (part == 0) ? Cb : (part == 1) ? Ck : Cv;
                    dst[(((size_t)(cc >> 5) * N_NODES + row) << 5) + (cc & 31)] = f2b(c);
                } else {
                    Cb[(size_t)row * M + col] = f2b(c);
                }
                if (STATS) cs[sn][r] = c;
            }
        }
    if (STATS) {   // per-row partial stats over this 64-col strip (BM=64)
        #pragma unroll
        for (int r = 0; r < 4; ++r) {
            float s  = cs[0][r] + cs[1][r];
            float s2 = cs[0][r] * cs[0][r] + cs[1][r] * cs[1][r];
            #pragma unroll
            for (int off = 1; off < 16; off <<= 1) {
                s  += __shfl_xor(s, off, 64);
                s2 += __shfl_xor(s2, off, 64);
            }
            if (l15 == 0) {
                int rl = wr * 16 + lhi * 4 + r;
                psA[rl][wc] = s; psA2[rl][wc] = s2;
            }
        }
        __syncthreads();
        if (tid < 64) {
            opsum [(size_t)(brow + tid) * 4 + by] = psA[tid][0] + psA[tid][1];
            opsum2[(size_t)(brow + tid) * 4 + by] = psA2[tid][0] + psA2[tid][1];
        }
    }
}

// ---------------- sparse attention: one (row,head) task per 64-lane wave --
// (round-17 proven body: f32 qreg, single-pass c<=64 + rare c>64 fallback)
#define TRLOAD(dst_, OFF_) \
    asm volatile("ds_read_b64_tr_b16 %0, %1 offset:" #OFF_ \
                 : "=v"(dst_) : "v"(trbase))
#define PVSUM(tv_) { \
    acc0 += b2f((unsigned short)tv_[0]); acc1 += b2f((unsigned short)tv_[1]); \
    acc0 += b2f((unsigned short)tv_[2]); acc1 += b2f((unsigned short)tv_[3]); }

__global__ __launch_bounds__(256) void attn_kernel(const unsigned short* __restrict__ qh,
        const unsigned short* __restrict__ kh, const unsigned short* __restrict__ vh,
        const unsigned* __restrict__ bitmap, unsigned short* __restrict__ y) {
    int bid = blockIdx.x, tid = threadIdx.x;
    int h = bid & 7;                       // all waves of this block: one head
    int wid = tid >> 6, lane = tid & 63;
    int n = ((bid >> 3) << 2) + wid;       // 8192 blocks x 4 waves = 4096 rows
    __shared__ int sIdx[4][CAP];
    __shared__ unsigned short Vst[4][2176];   // 16 jblocks x 136 (4x16 subtiles + pad)

    // q: all lanes hold the row's full 32-dim q (64B broadcast load)
    const unsigned short* qp = qh + (((size_t)h * N_NODES + n) << 5);
    float qreg[32];
    #pragma unroll
    for (int i = 0; i < 4; ++i) {
        short8 q8 = *(const short8*)(qp + i * 8);
        #pragma unroll
        for (int j = 0; j < 8; ++j) qreg[i * 8 + j] = b2f((unsigned short)q8[j]);
    }

    // bitmap scan: lane owns 2 words (uint2), prefix over 64 lanes
    uint2 w2 = ((const uint2*)(bitmap + (size_t)n * NWORDS))[lane];
    unsigned words[2] = {w2.x, w2.y};
    int pc = __popc(w2.x) + __popc(w2.y);
    int pre = pc;
    #pragma unroll
    for (int off = 1; off < 64; off <<= 1) {
        int u = __shfl_up(pre, off, 64);
        if (lane >= off) pre += u;
    }
    int c = __shfl(pre, 63, 64);
    int off = pre - pc;
    #pragma unroll
    for (int i = 0; i < 2; ++i) {
        unsigned word = words[i];
        int wbase = ((lane << 1) + i) << 5;
        while (word) {
            int bit = __ffs(word) - 1;
            word &= word - 1;
            if (off < CAP) sIdx[wid][off] = wbase + bit;
            ++off;
        }
    }
    c = min(c, CAP);
    for (int i = c + lane; i < CAP; i += 64) sIdx[wid][i] = 0;   // pad: safe index
    // (per-wave LDS: no block barrier needed)

    int idx = sIdx[wid][lane];
    const size_t hb = (size_t)h * N_NODES << 5;

    // V load first (consumed after softmax — long latency window)
    const unsigned short* va = vh + hb + ((size_t)idx << 5);
    short8 v0 = *(const short8*)(va);      short8 v1 = *(const short8*)(va + 8);
    short8 v2 = *(const short8*)(va + 16); short8 v3 = *(const short8*)(va + 24);
    // K gather
    const unsigned short* ka = kh + hb + ((size_t)idx << 5);
    short8 k0 = *(const short8*)(ka);      short8 k1 = *(const short8*)(ka + 8);
    short8 k2 = *(const short8*)(ka + 16); short8 k3 = *(const short8*)(ka + 24);

    float d0 = 0.f, d1 = 0.f, d2 = 0.f, d3 = 0.f;
    #pragma unroll
    for (int e = 0; e < 8; ++e) {
        d0 = fmaf(qreg[e],      b2f((unsigned short)k0[e]), d0);
        d1 = fmaf(qreg[8 + e],  b2f((unsigned short)k1[e]), d1);
        d2 = fmaf(qreg[16 + e], b2f((unsigned short)k2[e]), d2);
        d3 = fmaf(qreg[24 + e], b2f((unsigned short)k3[e]), d3);
    }
    const float sc = 0.17677669529663687f;   // 1/sqrt(32)
    float s = (lane < c) ? ((d0 + d1) + (d2 + d3)) * sc : -INFINITY;

    // single-pass softmax over the wave
    float bm = s;
    #pragma unroll
    for (int o2 = 32; o2; o2 >>= 1) bm = fmaxf(bm, __shfl_xor(bm, o2, 64));
    float p = (lane < c) ? __expf(s - bm) : 0.0f;
    float S = p;
    #pragma unroll
    for (int o2 = 32; o2; o2 >>= 1) S += __shfl_xor(S, o2, 64);

    // stage p-scaled V: elem(j,d) = (j>>2)*136 + (d>>4)*64 + (j&3)*16 + (d&15)
    {
        unsigned short* vr = &Vst[wid][(lane >> 2) * 136 + (lane & 3) * 16];
        *(uint4*)(vr + 0)  = scale8(v0, p);
        *(uint4*)(vr + 8)  = scale8(v1, p);
        *(uint4*)(vr + 64) = scale8(v2, p);
        *(uint4*)(vr + 72) = scale8(v3, p);
    }

    // PV: 8 tr-reads; lane&31 = output dim, lane>>5 = j-block parity (+272B)
    unsigned trbase = (unsigned)(uintptr_t)(&Vst[wid][0])
                    + ((unsigned)(lane >> 5) * 272u)
                    + (((unsigned)(lane >> 4) & 1u) << 7) + ((unsigned)(lane & 15) << 3);
    asm volatile("s_waitcnt lgkmcnt(0)" ::: "memory");   // Vst written
    short4v t0, t1, t2, t3, t4, t5, t6, t7;
    TRLOAD(t0, 0);    TRLOAD(t1, 544);  TRLOAD(t2, 1088); TRLOAD(t3, 1632);
    TRLOAD(t4, 2176); TRLOAD(t5, 2720); TRLOAD(t6, 3264); TRLOAD(t7, 3808);
    asm volatile("s_waitcnt lgkmcnt(0)" ::: "memory");
    __builtin_amdgcn_sched_barrier(0);

    float acc0 = 0.0f, acc1 = 0.0f;
    PVSUM(t0) PVSUM(t1) PVSUM(t2) PVSUM(t3)
    PVSUM(t4) PVSUM(t5) PVSUM(t6) PVSUM(t7)
    float acc = acc0 + acc1;

    // rare fallback: rows with c > 64 (online batches of 64, same tr path)
    if (c > 64) {
        float m_run = bm;
        for (int b0 = 64; b0 < c; b0 += 64) {
            int j = b0 + lane;
            int idx2 = sIdx[wid][b0 + lane];
            const unsigned short* va2 = vh + hb + ((size_t)idx2 << 5);
            short8 u0 = *(const short8*)(va2);      short8 u1 = *(const short8*)(va2 + 8);
            short8 u2 = *(const short8*)(va2 + 16); short8 u3 = *(const short8*)(va2 + 24);
            const unsigned short* ka2 = kh + hb + ((size_t)idx2 << 5);
            short8 e0 = *(const short8*)(ka2);      short8 e1 = *(const short8*)(ka2 + 8);
            short8 e2 = *(const short8*)(ka2 + 16); short8 e3 = *(const short8*)(ka2 + 24);
            float f0 = 0.f, f1 = 0.f, f2 = 0.f, f3 = 0.f;
            #pragma unroll
            for (int e = 0; e < 8; ++e) {
                f0 = fmaf(qreg[e],      b2f((unsigned short)e0[e]), f0);
                f1 = fmaf(qreg[8 + e],  b2f((unsigned short)e1[e]), f1);
                f2 = fmaf(qreg[16 + e], b2f((unsigned short)e2[e]), f2);
                f3 = fmaf(qreg[24 + e], b2f((unsigned short)e3[e]), f3);
            }
            float s2v = (j < c) ? ((f0 + f1) + (f2 + f3)) * sc : -INFINITY;
            float bm2 = s2v;
            #pragma unroll
            for (int o2 = 32; o2; o2 >>= 1) bm2 = fmaxf(bm2, __shfl_xor(bm2, o2, 64));
            float newM = fmaxf(m_run, bm2);
            float p2 = (j < c) ? __expf(s2v - newM) : 0.0f;
            float bs = p2;
            #pragma unroll
            for (int o2 = 32; o2; o2 >>= 1) bs += __shfl_xor(bs, o2, 64);
            float scale = __expf(m_run - newM);
            S = S * scale + bs;
            acc *= scale;
            unsigned short* vr = &Vst[wid][(lane >> 2) * 136 + (lane & 3) * 16];
            *(uint4*)(vr + 0)  = scale8(u0, p2);
            *(uint4*)(vr + 8)  = scale8(u1, p2);
            *(uint4*)(vr + 64) = scale8(u2, p2);
            *(uint4*)(vr + 72) = scale8(u3, p2);
            asm volatile("s_waitcnt lgkmcnt(0)" ::: "memory");
            short4v r0, r1, r2, r3, r4, r5, r6, r7;
            TRLOAD(r0, 0);    TRLOAD(r1, 544);  TRLOAD(r2, 1088); TRLOAD(r3, 1632);
            TRLOAD(r4, 2176); TRLOAD(r5, 2720); TRLOAD(r6, 3264); TRLOAD(r7, 3808);
            asm volatile("s_waitcnt lgkmcnt(0)" ::: "memory");
            __builtin_amdgcn_sched_barrier(0);
            float g0 = 0.f, g1v = 0.f;
            {
                float acc0b = 0.f, acc1b = 0.f;
                #define PVSUM2(tv_) { \
                    acc0b += b2f((unsigned short)tv_[0]); acc1b += b2f((unsigned short)tv_[1]); \
                    acc0b += b2f((unsigned short)tv_[2]); acc1b += b2f((unsigned short)tv_[3]); }
                PVSUM2(r0) PVSUM2(r1) PVSUM2(r2) PVSUM2(r3)
                PVSUM2(r4) PVSUM2(r5) PVSUM2(r6) PVSUM2(r7)
                g0 = acc0b; g1v = acc1b;
            }
            acc += g0 + g1v;
            m_run = newM;
        }
    }

    float tot = acc + __shfl_xor(acc, 32, 64);   // combine even/odd j-block halves
    if (lane < 32)
        y[(size_t)n * 256 + h * 32 + lane] = f2b(tot / S);
}

extern "C" void kernel_launch(void* const* d_in, const int* in_sizes, int n_in,
                              void* d_out, int out_size, void* d_ws, size_t ws_size,
                              hipStream_t stream) {
    const float* x   = (const float*)d_in[0];
    const int*   ei  = (const int*)d_in[1];
    const float* Wq  = (const float*)d_in[2];  const float* bq  = (const float*)d_in[3];
    const float* Wk  = (const float*)d_in[4];  const float* bk  = (const float*)d_in[5];
    const float* Wv  = (const float*)d_in[6];  const float* bv  = (const float*)d_in[7];
    const float* Wo  = (const float*)d_in[8];  const float* bo  = (const float*)d_in[9];
    const float* g1  = (const float*)d_in[10]; const float* b1  = (const float*)d_in[11];
    const float* g2  = (const float*)d_in[12]; const float* b2  = (const float*)d_in[13];
    const float* Wm1 = (const float*)d_in[14]; const float* bm1 = (const float*)d_in[15];
    const float* Wm2 = (const float*)d_in[16]; const float* bm2 = (const float*)d_in[17];
    float* out = (float*)d_out;
    int E = in_sizes[1] / 2;   // 135168
    int nadj = (E + 511) / 512;

    char* WS = (char*)d_ws;
    const size_t MB = 1u << 20;
    unsigned*       bitmap = (unsigned*)WS;                        // [0,2MB)
    int*            flag   = (int*)(WS + 2 * MB);                  // 4B
    float*          psum   = (float*)(WS + 2 * MB + 4096);         // 64KB [N][4]
    float*          psum2  = (float*)(WS + 2 * MB + 4096 + 65536); // 64KB
    unsigned short* wbf    = (unsigned short*)(WS + 3 * MB);       // 1MB
    unsigned short* y      = (unsigned short*)(WS + 4 * MB);       // 2MB
    float*          x1     = (float*)(WS + 6 * MB);                // 4MB
    unsigned short* m1     = (unsigned short*)(WS + 10 * MB);      // 4MB
    unsigned short* h      = (unsigned short*)(WS + 14 * MB);      // 2MB
    unsigned short* qh     = (unsigned short*)(WS + 16 * MB);      // 2MB [8][N][32]
    unsigned short* kh     = (unsigned short*)(WS + 18 * MB);      // 2MB
    unsigned short* vh     = (unsigned short*)(WS + 20 * MB);      // 2MB

    const unsigned short* WTqkv = wbf;            // q|k|v stacked along M
    const unsigned short* WTo   = wbf + 196608;
    const unsigned short* WTm1  = wbf + 262144;
    const unsigned short* WTm2  = wbf + 393216;

    // 1) convw (tiled transpose) + zero bitmap + detect + LN1 (wave-per-row)
    prep_kernel<<<1665, 256, 0, stream>>>(Wq, Wk, Wv, Wo, Wm1, Wm2, wbf,
                                          (uint4*)bitmap, ei, flag, x, g1, b1, h);
    // 2) build_adj (blocks [0,nadj)) + qkv GEMM (BM=64), head-major stores
    gemm_bf16<256, 64, 3, false, false><<<nadj + 768, 512, 0, stream>>>(h, nullptr,
            nullptr, nullptr, nullptr, nullptr, WTqkv, bq, bk, bv, nullptr,
            nullptr, qh, kh, vh, nullptr, nullptr, 768, ei, E, flag, bitmap, nadj);
    // 3) attention (wave64 per task, XCD-pinned heads, tr PV — r17 body)
    attn_kernel<<<8192, 256, 0, stream>>>(qh, kh, vh, bitmap, y);
    // 4) x1 = x + y @ Wo + bo   (+ per-row partial LN2 stats)
    gemm_bf16<256, 64, 2, false, true><<<dim3(64, 4), 512, 0, stream>>>(y, nullptr,
            nullptr, nullptr, nullptr, nullptr, WTo, bo, nullptr, nullptr, x,
            x1, nullptr, nullptr, nullptr, psum, psum2, 256, nullptr, 0, nullptr, nullptr, 0);
    // 5) m1 = gelu(LN2(x1) @ Wm1 + bm1)   (LN2 during A-staging, BM=64)
    gemm_bf16<256, 64, 1, true, false><<<dim3(64, 8), 512, 0, stream>>>(nullptr, x1,
            psum, psum2, g2, b2, WTm1, bm1, nullptr, nullptr, nullptr,
            nullptr, m1, nullptr, nullptr, nullptr, nullptr, 512, nullptr, 0, nullptr, nullptr, 0);
    // 6) out = x1 + m1 @ Wm2 + bm2
    gemm_bf16<512, 64, 2, false, false><<<dim3(64, 4), 512, 0, stream>>>(m1, nullptr,
            nullptr, nullptr, nullptr, nullptr, WTm2, bm2, nullptr, nullptr, x1,
            out, nullptr, nullptr, nullptr, nullptr, nullptr, 256, nullptr, 0, nullptr, nullptr, 0);
}